// Round 18
// baseline (397.874 us; speedup 1.0000x reference)
//
#include <hip/hip_runtime.h>

#define SLOPE 0.2f
#define BN_EPS 1e-5f

#define CSR_TILE 4096       // edges per tile
#define NBUCK_SH 9          // bucket = dst >> 9  (512 nodes per bucket)
#define BCAP 16384          // per-bucket slab capacity in tmp

typedef __attribute__((ext_vector_type(8))) short bf16x8;
typedef __attribute__((ext_vector_type(4))) float f32x4;

__device__ __forceinline__ float wave_sum(float v){
  #pragma unroll
  for(int o=32;o;o>>=1) v += __shfl_xor(v,o);
  return v;
}
__device__ __forceinline__ float wave_max(float v){
  #pragma unroll
  for(int o=32;o;o>>=1) v = fmaxf(v,__shfl_xor(v,o));
  return v;
}
__device__ __forceinline__ unsigned pack_bf16(float a, float b){
  unsigned ua=__float_as_uint(a), ub=__float_as_uint(b);
  ua += 0x7fffu + ((ua>>16)&1u);
  ub += 0x7fffu + ((ub>>16)&1u);
  return (ua>>16) | (ub & 0xffff0000u);
}
__device__ __forceinline__ float bf_lo(unsigned u){ return __uint_as_float(u<<16); }
__device__ __forceinline__ float bf_hi(unsigned u){ return __uint_as_float(u & 0xffff0000u); }

// ---------------- weight transposes + cursor zeroing in one launch
__global__ __launch_bounds__(256) void wtrans2(const float* __restrict__ W0,
    const float* __restrict__ W1, unsigned* __restrict__ Wt0, unsigned* __restrict__ Wt1,
    int* __restrict__ cursor){
  int idx = blockIdx.x*256 + threadIdx.x;
  if(blockIdx.x < 64){
    int c = idx >> 7, kp = idx & 127;          // W0: K=256 -> 128 kpairs
    Wt0[(size_t)c*128 + kp] = pack_bf16(W0[(size_t)(2*kp)*128 + c], W0[(size_t)(2*kp+1)*128 + c]);
  } else {
    int i2 = idx - 64*256;
    int c = i2 >> 6, kp = i2 & 63;             // W1: K=128 -> 64 kpairs
    Wt1[(size_t)c*64 + kp] = pack_bf16(W1[(size_t)(2*kp)*128 + c], W1[(size_t)(2*kp+1)*128 + c]);
    if(blockIdx.x == 95) cursor[threadIdx.x] = 0;
  }
}

// ---------------- FAT kernel: [0, ncsr) = CSR scatter; [ncsr, ...) = LDS-free MFMA GEMM
// GEMM: one wave per 16-row x 128-col stripe. A fragments loaded direct global->reg
// (lane&15 = row, lane>>4 = k-group), B from L2-resident Wt. No barriers, no LDS.
template<int AF32, int KK>
__global__ __launch_bounds__(256, 4) void fat_kernel(const void* __restrict__ Aptr,
    const unsigned* __restrict__ Wt, unsigned* __restrict__ outb,
    const float* __restrict__ al, const float* __restrict__ ar,
    float* __restrict__ el, float* __restrict__ er, int n,
    const int* __restrict__ src, const int* __restrict__ dst,
    int* __restrict__ cursor, unsigned* __restrict__ tmp, int E, int nbuck, int ncsr){
  constexpr int K2 = KK >> 1;      // kpairs per row
  constexpr int KS = KK >> 5;      // 32-k steps
  __shared__ unsigned smem[6656];  // used only by CSR blocks
  int t = threadIdx.x;

  if((int)blockIdx.x < ncsr){
    // ================= CSR part =================
    unsigned* eb  = smem;                       // [4096]
    short*    ebb = (short*)(smem + 4096);      // [4096]
    int*      hist= (int*)(smem + 6144);        // [256]
    int*      basel=(int*)(smem + 6400);        // [256]
    hist[t] = 0;
    __syncthreads();
    int base = blockIdx.x * CSR_TILE;
    int cnt  = min(CSR_TILE, E - base);
    for(int k = t; k < cnt; k += 256){
      int d = dst[base + k];
      int s = src[base + k];
      int b = d >> NBUCK_SH;
      eb[k]  = (unsigned)s | ((unsigned)(d & ((1<<NBUCK_SH)-1)) << 17);
      ebb[k] = (short)b;
      atomicAdd(&hist[b], 1);
    }
    __syncthreads();
    if(t < nbuck && hist[t] > 0)
      basel[t] = atomicAdd(&cursor[t], hist[t]);
    __syncthreads();
    hist[t] = 0;
    __syncthreads();
    for(int k = t; k < cnt; k += 256){
      int b = ebb[k];
      int r = atomicAdd(&hist[b], 1);
      tmp[(size_t)b*BCAP + basel[b] + r] = eb[k];
    }
    return;
  }

  // ================= GEMM part (no LDS, no barriers) =================
  int bid = blockIdx.x - ncsr;
  int w = t >> 6, l = t & 63;
  int rl = l & 15, kg = l >> 4;
  int wrow0 = (bid*4 + w) * 16;          // this wave's 16-row stripe
  if(wrow0 >= n) return;                 // wave-uniform exit (no barriers below)
  int growl = wrow0 + rl;                // row this lane loads A for
  bool rok = growl < n;

  f32x4 zero4 = {0.f,0.f,0.f,0.f};
  f32x4 acc[8];
  #pragma unroll
  for(int j=0;j<8;j++) acc[j] = zero4;

  #pragma unroll 2
  for(int kt = 0; kt < KS; ++kt){
    bf16x8 a;
    if(AF32){
      const float* A = (const float*)Aptr;
      float4 f0 = make_float4(0.f,0.f,0.f,0.f);
      float4 f1 = make_float4(0.f,0.f,0.f,0.f);
      if(rok){
        const float* ap = A + (size_t)growl*KK + kt*32 + kg*8;
        f0 = *(const float4*)ap;
        f1 = *(const float4*)(ap+4);
      }
      uint4 uv;
      uv.x = pack_bf16(f0.x,f0.y); uv.y = pack_bf16(f0.z,f0.w);
      uv.z = pack_bf16(f1.x,f1.y); uv.w = pack_bf16(f1.z,f1.w);
      a = __builtin_bit_cast(bf16x8, uv);
    } else {
      const unsigned* A = (const unsigned*)Aptr;
      uint4 uv = make_uint4(0,0,0,0);
      if(rok) uv = *(const uint4*)(A + (size_t)growl*K2 + kt*16 + kg*4);
      a = __builtin_bit_cast(bf16x8, uv);
    }
    #pragma unroll
    for(int j=0;j<8;j++){
      bf16x8 b = *(const bf16x8*)&Wt[(size_t)(j*16 + rl)*K2 + kt*16 + kg*4];
      acc[j] = __builtin_amdgcn_mfma_f32_16x16x32_bf16(a, b, acc[j], 0, 0, 0);
    }
  }

  // C-write (direct scatter): within col-tile j, col=lane&15, row=(lane>>4)*4+g
  #pragma unroll
  for(int j=0;j<8;j++){
    #pragma unroll
    for(int g=0;g<4;g++){
      float v  = acc[j][g];
      float vp = __shfl_xor(v, 1);
      if(!(l & 1)){
        unsigned pv = pack_bf16(v, vp);
        int grow = wrow0 + kg*4 + g;
        int gcol = j*16 + rl;
        if(grow < n) outb[(size_t)grow*64 + (gcol>>1)] = pv;
      }
    }
  }

  // fused el/er: wave covers all 128 cols (both heads) of its 16 rows
  {
    float alv[8], arv[8];
    #pragma unroll
    for(int j=0;j<8;j++){
      int c = j*16 + rl;
      alv[j] = al[c]; arv[j] = ar[c];
    }
    #pragma unroll
    for(int g=0;g<4;g++){
      float pe0 = acc[0][g]*alv[0] + acc[1][g]*alv[1] + acc[2][g]*alv[2] + acc[3][g]*alv[3];
      float qe0 = acc[0][g]*arv[0] + acc[1][g]*arv[1] + acc[2][g]*arv[2] + acc[3][g]*arv[3];
      float pe1 = acc[4][g]*alv[4] + acc[5][g]*alv[5] + acc[6][g]*alv[6] + acc[7][g]*alv[7];
      float qe1 = acc[4][g]*arv[4] + acc[5][g]*arv[5] + acc[6][g]*arv[6] + acc[7][g]*arv[7];
      #pragma unroll
      for(int o=8;o;o>>=1){
        pe0 += __shfl_xor(pe0,o); qe0 += __shfl_xor(qe0,o);
        pe1 += __shfl_xor(pe1,o); qe1 += __shfl_xor(qe1,o);
      }
      if(rl == 0){
        int grow = wrow0 + kg*4 + g;
        if(grow < n){
          *(float2*)&el[(size_t)grow*2] = make_float2(pe0, pe1);
          *(float2*)&er[(size_t)grow*2] = make_float2(qe0, qe1);
        }
      }
    }
  }
}

// ---------------- csrD: self-scan of bucket counts + per-bucket rowptr/esrc
__global__ __launch_bounds__(512) void csrD(const unsigned* __restrict__ tmp,
    const int* __restrict__ cursor, int* __restrict__ rowptr,
    int* __restrict__ esrc, int N, int E, int nbuck){
  __shared__ int sc[256];
  __shared__ int hist[512];
  __shared__ int ls[512];
  int t = threadIdx.x;
  int b = blockIdx.x;
  if(t < 256) sc[t] = (t < nbuck) ? cursor[t] : 0;
  __syncthreads();
  for(int o=1;o<256;o<<=1){
    int x = (t>=o && t<256) ? sc[t-o] : 0;
    __syncthreads();
    if(t < 256) sc[t] += x;
    __syncthreads();
  }
  __shared__ int s_base, s_cnt;
  if(t == 0){ s_cnt = cursor[b]; s_base = sc[b] - s_cnt; }
  __syncthreads();
  int base = s_base, cnt = s_cnt;
  const unsigned* tp = tmp + (size_t)b*BCAP;
  int n0 = b << NBUCK_SH;
  int nn = min(512, N - n0);
  hist[t] = 0;
  __syncthreads();
  for(int i = t; i < cnt; i += 512)
    atomicAdd(&hist[tp[i] >> 17], 1);
  __syncthreads();
  int v = hist[t];
  ls[t] = v; __syncthreads();
  for(int o=1;o<512;o<<=1){
    int x = (t>=o) ? ls[t-o] : 0;
    __syncthreads();
    ls[t] += x;
    __syncthreads();
  }
  int rp = ls[t] - v;
  if(t < nn) rowptr[n0 + t] = base + rp;
  if(b == nbuck-1 && t == 0) rowptr[N] = E;
  __syncthreads();
  hist[t] = rp;
  __syncthreads();
  for(int i = t; i < cnt; i += 512){
    unsigned v2 = tp[i];
    int dl = v2 >> 17;
    int s  = v2 & 0x1FFFF;
    int r  = atomicAdd(&hist[dl], 1);
    esrc[base + r] = s;
  }
}

// ---- 8-deep gather/accumulate over one ≤64-edge chunk
__device__ __forceinline__ void agg_chunk(const unsigned* __restrict__ featb,
    int s, unsigned wp, int nval, int lane, int shamt, float& acc0, float& acc1){
  for(int e = 0; e < nval; e += 8){
    unsigned v[8]; float w[8];
    #pragma unroll
    for(int u=0;u<8;u++){
      int se       = __shfl(s,  e+u);
      unsigned wpe = __shfl(wp, e+u);
      w[u] = __uint_as_float((wpe << shamt) & 0xffff0000u);
      v[u] = featb[((unsigned)se << 6) + (unsigned)lane];
    }
    #pragma unroll
    for(int u=0;u<8;u++){
      acc0 += bf_lo(v[u]) * w[u];
      acc1 += bf_hi(v[u]) * w[u];
    }
  }
}

// ---------------- GAT aggregation: wave per dst node, bf16 gather -> bf16 out
__global__ __launch_bounds__(256) void agg_kernel(const unsigned* __restrict__ featb,
    const float* __restrict__ el, const float* __restrict__ er,
    const int* __restrict__ rowptr, const int* __restrict__ esrc,
    const float* __restrict__ bias, unsigned* __restrict__ outp, int n){
  int wid = (blockIdx.x*blockDim.x + threadIdx.x) >> 6;
  int lane = threadIdx.x & 63;
  if(wid >= n) return;
  int beg = rowptr[wid], end = rowptr[wid+1];
  int deg = end - beg;
  float2 erd = *(const float2*)&er[(size_t)wid*2];
  int shamt = (lane < 32) ? 16 : 0;
  float acc0 = 0.f, acc1 = 0.f;

  if(deg <= 64){
    int s = (lane < deg) ? esrc[beg + lane] : 0;
    float2 elv = *(const float2*)&el[(size_t)s*2];
    float e0 = elv.x + erd.x, e1 = elv.y + erd.y;
    e0 = (e0 >= 0.f) ? e0 : SLOPE*e0;
    e1 = (e1 >= 0.f) ? e1 : SLOPE*e1;
    float p0 = __expf(e0), p1 = __expf(e1);
    if(lane >= deg){ p0 = 0.f; p1 = 0.f; }
    float d0 = wave_sum(p0), d1 = wave_sum(p1);
    unsigned wp = pack_bf16(p0 / fmaxf(d0, 1e-16f), p1 / fmaxf(d1, 1e-16f));
    agg_chunk(featb, s, wp, deg, lane, shamt, acc0, acc1);
  } else {
    float d0 = 0.f, d1 = 0.f;
    for(int base = beg; base < end; base += 64){
      int idx = base + lane;
      int s = (idx < end) ? esrc[idx] : 0;
      float2 elv = *(const float2*)&el[(size_t)s*2];
      float e0 = elv.x + erd.x, e1 = elv.y + erd.y;
      e0 = (e0 >= 0.f) ? e0 : SLOPE*e0;
      e1 = (e1 >= 0.f) ? e1 : SLOPE*e1;
      float p0 = __expf(e0), p1 = __expf(e1);
      if(idx >= end){ p0 = 0.f; p1 = 0.f; }
      d0 += p0; d1 += p1;
    }
    d0 = wave_sum(d0); d1 = wave_sum(d1);
    float inv0 = 1.0f / fmaxf(d0, 1e-16f);
    float inv1 = 1.0f / fmaxf(d1, 1e-16f);
    for(int base = beg; base < end; base += 64){
      int idx = base + lane;
      int s = (idx < end) ? esrc[idx] : 0;
      float2 elv = *(const float2*)&el[(size_t)s*2];
      float e0 = elv.x + erd.x, e1 = elv.y + erd.y;
      e0 = (e0 >= 0.f) ? e0 : SLOPE*e0;
      e1 = (e1 >= 0.f) ? e1 : SLOPE*e1;
      unsigned wp = pack_bf16(__expf(e0) * inv0, __expf(e1) * inv1);
      if(idx >= end) wp = 0;
      agg_chunk(featb, s, wp, min(64, end - base), lane, shamt, acc0, acc1);
    }
  }
  float2 bb = *(const float2*)&bias[2*lane];
  outp[(size_t)wid*64 + lane] =
      pack_bf16(fmaxf(acc0 + bb.x, 0.f), fmaxf(acc1 + bb.y, 0.f));
}

// ---------------- head: relu(h@Wout+bout) @ Wfc + bfc + per-block BN partials
__global__ __launch_bounds__(256) void head_kernel(const unsigned* __restrict__ h,
    const float* __restrict__ Wout, const float* __restrict__ bout,
    const float* __restrict__ Wfc, const float* __restrict__ bfc,
    float* __restrict__ hfc, float* __restrict__ psum, float* __restrict__ psum2,
    int n){
  __shared__ float sAT[32][68];
  __shared__ float sWo[32][68];
  __shared__ float sOT[64][68];
  __shared__ float sF [64][68];
  int t = threadIdx.x;
  int cx = t & 15;
  int ry = t >> 4;
  int row0 = blockIdx.x * 64;

  {
    int kr = t >> 4;
    int c0 = (t & 15) * 4;
    #pragma unroll
    for(int i=0;i<4;i++)
      *(float4*)&sF[kr+i*16][c0] = *(const float4*)&Wfc[(size_t)(kr+i*16)*64 + c0];
  }

  float acc[4][4] = {};
  for(int k0 = 0; k0 < 128; k0 += 32){
    #pragma unroll
    for(int u=0;u<2;u++){
      int f4 = t*2 + u;
      int r  = f4 >> 3;
      int kc = (f4 & 7) * 4;
      int gr = row0 + r;
      uint2 v = make_uint2(0,0);
      if(gr < n) v = *(const uint2*)&h[(size_t)gr*64 + ((k0+kc)>>1)];
      sAT[kc+0][r] = bf_lo(v.x);
      sAT[kc+1][r] = bf_hi(v.x);
      sAT[kc+2][r] = bf_lo(v.y);
      sAT[kc+3][r] = bf_hi(v.y);
    }
    #pragma unroll
    for(int u=0;u<2;u++){
      int f4 = t*2 + u;
      int kr = f4 >> 4;
      int c0 = (f4 & 15) * 4;
      *(float4*)&sWo[kr][c0] = *(const float4*)&Wout[(size_t)(k0+kr)*64 + c0];
    }
    __syncthreads();
    #pragma unroll 8
    for(int kk = 0; kk < 32; ++kk){
      float4 a4 = *(const float4*)&sAT[kk][ry*4];
      float4 b4 = *(const float4*)&sWo[kk][cx*4];
      float a[4] = {a4.x,a4.y,a4.z,a4.w};
      float b[4] = {b4.x,b4.y,b4.z,b4.w};
      #pragma unroll
      for(int i=0;i<4;i++)
        #pragma unroll
        for(int j=0;j<4;j++) acc[i][j] += a[i]*b[j];
    }
    __syncthreads();
  }
  {
    float4 bb = *(const float4*)&bout[cx*4];
    float bv[4] = {bb.x,bb.y,bb.z,bb.w};
    #pragma unroll
    for(int i=0;i<4;i++)
      #pragma unroll
      for(int j=0;j<4;j++)
        sOT[cx*4+j][ry*4+i] = fmaxf(acc[i][j] + bv[j], 0.f);
  }
  __syncthreads();
  float acc2[4][4] = {};
  #pragma unroll 8
  for(int kk = 0; kk < 64; ++kk){
    float4 a4 = *(const float4*)&sOT[kk][ry*4];
    float4 b4 = *(const float4*)&sF [kk][cx*4];
    float a[4] = {a4.x,a4.y,a4.z,a4.w};
    float b[4] = {b4.x,b4.y,b4.z,b4.w};
    #pragma unroll
    for(int i=0;i<4;i++)
      #pragma unroll
      for(int j=0;j<4;j++) acc2[i][j] += a[i]*b[j];
  }
  __syncthreads();   // done reading sOT; reuse it for final values
  {
    float4 bb = *(const float4*)&bfc[cx*4];
    float bv[4] = {bb.x,bb.y,bb.z,bb.w};
    #pragma unroll
    for(int i=0;i<4;i++){
      int gr = row0 + ry*4 + i;
      float o0 = acc2[i][0]+bv[0], o1 = acc2[i][1]+bv[1];
      float o2 = acc2[i][2]+bv[2], o3 = acc2[i][3]+bv[3];
      if(gr < n){
        *(float4*)&hfc[(size_t)gr*64 + cx*4] = make_float4(o0,o1,o2,o3);
        sOT[ry*4+i][cx*4+0] = o0;
        sOT[ry*4+i][cx*4+1] = o1;
        sOT[ry*4+i][cx*4+2] = o2;
        sOT[ry*4+i][cx*4+3] = o3;
      } else {
        sOT[ry*4+i][cx*4+0] = 0.f;
        sOT[ry*4+i][cx*4+1] = 0.f;
        sOT[ry*4+i][cx*4+2] = 0.f;
        sOT[ry*4+i][cx*4+3] = 0.f;
      }
    }
  }
  __syncthreads();
  // deterministic per-block column sums over 64 rows
  if(t < 64){
    float s = 0.f, s2 = 0.f;
    #pragma unroll 8
    for(int r = 0; r < 64; ++r){
      float v = sOT[r][t];
      s += v; s2 += v*v;
    }
    psum [(size_t)blockIdx.x*64 + t] = s;
    psum2[(size_t)blockIdx.x*64 + t] = s2;
  }
}

// ---------------- BN reduce stage 1: 128 blocks over nb head-partials
__global__ __launch_bounds__(256) void bn_red(const float* __restrict__ psum,
    const float* __restrict__ psum2, float* __restrict__ rsum,
    float* __restrict__ rsum2, int nb){
  __shared__ float ls[256], ls2[256];
  int t = threadIdx.x; int c = t & 63; int g = t >> 6;
  int R = (nb + 127) / 128;
  int r0 = blockIdx.x * R;
  int r1 = min(nb, r0 + R);
  float s = 0.f, s2 = 0.f;
  for(int r = r0 + g; r < r1; r += 4){
    s  += psum [(size_t)r*64 + c];
    s2 += psum2[(size_t)r*64 + c];
  }
  ls[t] = s; ls2[t] = s2;
  __syncthreads();
  if(t < 64){
    rsum [(size_t)blockIdx.x*64 + t] = ls[t]+ls[t+64]+ls[t+128]+ls[t+192];
    rsum2[(size_t)blockIdx.x*64 + t] = ls2[t]+ls2[t+64]+ls2[t+128]+ls2[t+192];
  }
}

// ---------------- BN finalize (reduces 128 second-level partials)
__global__ __launch_bounds__(256) void bn_fin(const float* __restrict__ rsum,
    const float* __restrict__ rsum2, const float* __restrict__ gamma,
    const float* __restrict__ beta, float* __restrict__ scsh, int n){
  __shared__ float ls[256], ls2[256];
  int t = threadIdx.x; int c = t & 63; int g = t >> 6;
  float s = 0.f, s2 = 0.f;
  for(int b = g; b < 128; b += 4){
    s  += rsum [(size_t)b*64 + c];
    s2 += rsum2[(size_t)b*64 + c];
  }
  ls[t] = s; ls2[t] = s2;
  __syncthreads();
  if(t < 64){
    s  = ls[t]+ls[t+64]+ls[t+128]+ls[t+192];
    s2 = ls2[t]+ls2[t+64]+ls2[t+128]+ls2[t+192];
    float mu  = s / n;
    float var = s2 / n - mu*mu;
    float scale = rsqrtf(var + BN_EPS) * gamma[t];
    scsh[t]    = scale;
    scsh[64+t] = beta[t] - mu*scale;
  }
}

// ---------------- BN apply + row softmax -> p
__global__ __launch_bounds__(256) void bn_softmax(const float* __restrict__ hfc,
    const float* __restrict__ scsh, float* __restrict__ p, int n){
  int wid = (blockIdx.x*blockDim.x + threadIdx.x) >> 6;
  int lane = threadIdx.x & 63;
  if(wid >= n) return;
  float y = hfc[(size_t)wid*64 + lane]*scsh[lane] + scsh[64+lane];
  float m = wave_max(y);
  float e = expf(y - m);
  float s = wave_sum(e);
  p[(size_t)wid*64 + lane] = e / s;
}

// ---------------- loss
__global__ __launch_bounds__(256) void loss1(const float* __restrict__ p,
    const int* __restrict__ train, const int* __restrict__ label,
    float* __restrict__ part, int ntrain){
  int lane = threadIdx.x & 63; int w = threadIdx.x >> 6;
  int gw = blockIdx.x*4 + w; int nw = gridDim.x*4;
  float acc = 0.f;
  for(int t = gw; t < ntrain; t += nw){
    int node = train[t];
    float v = p[(size_t)node*64 + lane];
    float m = wave_max(v);
    float e = expf(v - m);
    float s = wave_sum(e);
    float logp = (v - m) - logf(s);
    int lab = label[node];
    if(lane == lab) acc += logp;
  }
  acc = wave_sum(acc);
  __shared__ float ls[4];
  if(lane == 0) ls[w] = acc;
  __syncthreads();
  if(threadIdx.x == 0) part[blockIdx.x] = ls[0]+ls[1]+ls[2]+ls[3];
}

__global__ void loss2(const float* __restrict__ part, float* __restrict__ out,
                      int nb, int ntrain){
  if(threadIdx.x == 0){
    float s = 0.f;
    for(int i=0;i<nb;i++) s += part[i];
    out[0] = -s / (float)ntrain;
  }
}

extern "C" void kernel_launch(void* const* d_in, const int* in_sizes, int n_in,
                              void* d_out, int out_size, void* d_ws, size_t ws_size,
                              hipStream_t stream){
  const float* feature = (const float*)d_in[0];
  const int*   label   = (const int*)d_in[1];
  const int*   train   = (const int*)d_in[2];
  const int*   src     = (const int*)d_in[3];
  const int*   dst     = (const int*)d_in[4];
  const float* W0   = (const float*)d_in[5];
  const float* al0  = (const float*)d_in[6];
  const float* ar0  = (const float*)d_in[7];
  const float* b0   = (const float*)d_in[8];
  const float* W1   = (const float*)d_in[9];
  const float* al1  = (const float*)d_in[10];
  const float* ar1  = (const float*)d_in[11];
  const float* b1   = (const float*)d_in[12];
  const float* Wout = (const float*)d_in[13];
  const float* bout = (const float*)d_in[14];
  const float* Wfc  = (const float*)d_in[15];
  const float* bfc  = (const float*)d_in[16];
  const float* gamma= (const float*)d_in[17];
  const float* beta = (const float*)d_in[18];

  const int N  = in_sizes[1];
  const int NT = in_sizes[2];
  const int E  = in_sizes[3];

  const int nbuck  = (N + (1<<NBUCK_SH) - 1) >> NBUCK_SH;   // 196
  const int ntiles = (E + CSR_TILE - 1) / CSR_TILE;         // 391
  const int ngemm  = (N + 63) / 64;                         // waves*16 rows: 4 waves/block = 64 rows
  const int nhead  = (N + 63) / 64;                         // 1563

  size_t off = 0;
  auto alloc = [&](size_t bytes)->void*{
    void* pp = (char*)d_ws + off;
    off += (bytes + 255) & ~(size_t)255;
    return pp;
  };
  unsigned* featb16 = (unsigned*)alloc((size_t)N*64*4);
  unsigned* hbuf2   = (unsigned*)alloc((size_t)N*64*4);   // also tmp slabs
  float* el      = (float*)alloc((size_t)N*2*4);
  float* er      = (float*)alloc((size_t)N*2*4);
  int*   rowptr  = (int*)alloc((size_t)(N+1)*4);
  int*   esrc    = (int*)alloc((size_t)E*4);
  int*   cursor  = (int*)alloc((size_t)256*4);
  unsigned* Wt0  = (unsigned*)alloc((size_t)128*128*4);
  unsigned* Wt1  = (unsigned*)alloc((size_t)128*64*4);
  float* psum    = (float*)alloc((size_t)(nhead+1)*64*4);
  float* psum2   = (float*)alloc((size_t)(nhead+1)*64*4);
  float* rsum    = (float*)alloc((size_t)128*64*4);
  float* rsum2   = (float*)alloc((size_t)128*64*4);
  float* scsh    = (float*)alloc(128*4);
  float* lpart   = (float*)alloc(256*4);
  float* hfc     = (float*)featb16;      // reuse: featb16 dead after agg L1
  unsigned* tmp  = hbuf2;                // reuse: hbuf2 first written by agg L0

  float* p_out   = (float*)d_out;
  float* loss_out= (float*)d_out + (size_t)N*64;

  const int nwaveblk = (N + 3) / 4;

  // 1. weight prep + cursor zeroing
  wtrans2<<<96, 256, 0, stream>>>(W0, W1, Wt0, Wt1, cursor);

  // 2. CSR scatter || GEMM layer 0 (LDS-free gemm; one fat dispatch)
  fat_kernel<1,256><<<ntiles + ngemm, 256, 0, stream>>>(feature, Wt0, featb16,
      al0, ar0, el, er, N, src, dst, cursor, tmp, E, nbuck, ntiles);

  // 3. CSR finalize
  csrD<<<nbuck, 512, 0, stream>>>(tmp, cursor, rowptr, esrc, N, E, nbuck);

  // 4. aggregation layer 0
  agg_kernel<<<nwaveblk, 256, 0, stream>>>(featb16, el, er, rowptr, esrc, b0, hbuf2, N);

  // 5. GEMM layer 1 (ncsr = 0)
  fat_kernel<0,128><<<ngemm, 256, 0, stream>>>(hbuf2, Wt1, featb16,
      al1, ar1, el, er, N, src, dst, cursor, tmp, E, nbuck, 0);

  // 6. aggregation layer 1
  agg_kernel<<<nwaveblk, 256, 0, stream>>>(featb16, el, er, rowptr, esrc, b1, hbuf2, N);

  // 7. dense head + BN partials
  head_kernel<<<nhead, 256, 0, stream>>>(hbuf2, Wout, bout, Wfc, bfc, hfc, psum, psum2, N);

  // 8. BN reduce (two-stage deterministic tree)
  bn_red<<<128, 256, 0, stream>>>(psum, psum2, rsum, rsum2, nhead);
  bn_fin<<<1, 256, 0, stream>>>(rsum, rsum2, gamma, beta, scsh, N);

  // 9. BN apply + softmax
  bn_softmax<<<nwaveblk, 256, 0, stream>>>(hfc, scsh, p_out, N);

  // 10-11. loss
  loss1<<<40, 256, 0, stream>>>(p_out, train, label, lpart, NT);
  loss2<<<1, 64, 0, stream>>>(lpart, loss_out, 40, NT);
}

// Round 19
// 364.991 us; speedup vs baseline: 1.0901x; 1.0901x over previous
//
#include <hip/hip_runtime.h>

#define SLOPE 0.2f
#define BN_EPS 1e-5f

#define CSR_TILE 4096       // edges per tile
#define NBUCK_SH 9          // bucket = dst >> 9  (512 nodes per bucket)
#define BCAP 16384          // per-bucket slab capacity in tmp

typedef __attribute__((ext_vector_type(8))) short bf16x8;
typedef __attribute__((ext_vector_type(4))) float f32x4;

__device__ __forceinline__ float wave_sum(float v){
  #pragma unroll
  for(int o=32;o;o>>=1) v += __shfl_xor(v,o);
  return v;
}
__device__ __forceinline__ float wave_max(float v){
  #pragma unroll
  for(int o=32;o;o>>=1) v = fmaxf(v,__shfl_xor(v,o));
  return v;
}
__device__ __forceinline__ unsigned pack_bf16(float a, float b){
  unsigned ua=__float_as_uint(a), ub=__float_as_uint(b);
  ua += 0x7fffu + ((ua>>16)&1u);
  ub += 0x7fffu + ((ub>>16)&1u);
  return (ua>>16) | (ub & 0xffff0000u);
}
__device__ __forceinline__ float bf_lo(unsigned u){ return __uint_as_float(u<<16); }
__device__ __forceinline__ float bf_hi(unsigned u){ return __uint_as_float(u & 0xffff0000u); }

// ---------------- weight transposes + cursor zeroing in one launch
__global__ __launch_bounds__(256) void wtrans2(const float* __restrict__ W0,
    const float* __restrict__ W1, unsigned* __restrict__ Wt0, unsigned* __restrict__ Wt1,
    int* __restrict__ cursor){
  int idx = blockIdx.x*256 + threadIdx.x;
  if(blockIdx.x < 64){
    int c = idx >> 7, kp = idx & 127;          // W0: K=256 -> 128 kpairs
    Wt0[(size_t)c*128 + kp] = pack_bf16(W0[(size_t)(2*kp)*128 + c], W0[(size_t)(2*kp+1)*128 + c]);
  } else {
    int i2 = idx - 64*256;
    int c = i2 >> 6, kp = i2 & 63;             // W1: K=128 -> 64 kpairs
    Wt1[(size_t)c*64 + kp] = pack_bf16(W1[(size_t)(2*kp)*128 + c], W1[(size_t)(2*kp+1)*128 + c]);
    if(blockIdx.x == 95) cursor[threadIdx.x] = 0;
  }
}

// ---------------- FAT kernel: [0, ncsr) = CSR scatter; [ncsr, ...) = MFMA GEMM
template<int AF32, int KK>
__global__ __launch_bounds__(256) void fat_kernel(const void* __restrict__ Aptr,
    const unsigned* __restrict__ Wt, unsigned* __restrict__ outb,
    const float* __restrict__ al, const float* __restrict__ ar,
    float* __restrict__ el, float* __restrict__ er, int n,
    const int* __restrict__ src, const int* __restrict__ dst,
    int* __restrict__ cursor, unsigned* __restrict__ tmp, int E, int nbuck, int ncsr){
  constexpr int K2 = KK >> 1;
  constexpr int KT = KK >> 6;
  __shared__ unsigned smem[6656];      // 26.6 KB union
  int t = threadIdx.x;

  if((int)blockIdx.x < ncsr){
    // ================= CSR part =================
    unsigned* eb  = smem;                       // [4096]
    short*    ebb = (short*)(smem + 4096);      // [4096]
    int*      hist= (int*)(smem + 6144);        // [256]
    int*      basel=(int*)(smem + 6400);        // [256]
    hist[t] = 0;
    __syncthreads();
    int base = blockIdx.x * CSR_TILE;
    int cnt  = min(CSR_TILE, E - base);
    for(int k = t; k < cnt; k += 256){
      int d = dst[base + k];
      int s = src[base + k];
      int b = d >> NBUCK_SH;
      eb[k]  = (unsigned)s | ((unsigned)(d & ((1<<NBUCK_SH)-1)) << 17);
      ebb[k] = (short)b;
      atomicAdd(&hist[b], 1);
    }
    __syncthreads();
    if(t < nbuck && hist[t] > 0)
      basel[t] = atomicAdd(&cursor[t], hist[t]);
    __syncthreads();
    hist[t] = 0;
    __syncthreads();
    for(int k = t; k < cnt; k += 256){
      int b = ebb[k];
      int r = atomicAdd(&hist[b], 1);
      tmp[(size_t)b*BCAP + basel[b] + r] = eb[k];
    }
    return;
  }

  // ================= GEMM part =================
  unsigned (*sA)[36] = (unsigned(*)[36])smem;
  int bid = blockIdx.x - ncsr;
  int w = t >> 6, l = t & 63;
  int wr = (w >> 1) * 64, wc = (w & 1) * 64;
  int row0 = bid * 128;

  int srow[4], sslot[4];
  #pragma unroll
  for(int i=0;i<4;i++){ int u4 = t + i*256; srow[i] = u4>>3; sslot[i] = u4&7; }

  uint4 pa[4][2];

  auto load_tile = [&](int kt){
    if(AF32){
      const float* A = (const float*)Aptr;
      #pragma unroll
      for(int i=0;i<4;i++){
        int gr = row0 + srow[i];
        pa[i][0] = make_uint4(0,0,0,0);
        pa[i][1] = make_uint4(0,0,0,0);
        if(gr < n){
          const unsigned* ap = (const unsigned*)(A + (size_t)gr*KK + kt*64 + sslot[i]*8);
          pa[i][0] = *(const uint4*)ap;
          pa[i][1] = *(const uint4*)(ap+4);
        }
      }
    } else {
      const unsigned* A = (const unsigned*)Aptr;
      #pragma unroll
      for(int i=0;i<4;i++){
        int gr = row0 + srow[i];
        pa[i][0] = make_uint4(0,0,0,0);
        if(gr < n) pa[i][0] = *(const uint4*)(A + (size_t)gr*K2 + kt*32 + sslot[i]*4);
      }
    }
  };

  auto store_tile = [&](){
    if(AF32){
      #pragma unroll
      for(int i=0;i<4;i++){
        uint4 v;
        v.x = pack_bf16(__uint_as_float(pa[i][0].x), __uint_as_float(pa[i][0].y));
        v.y = pack_bf16(__uint_as_float(pa[i][0].z), __uint_as_float(pa[i][0].w));
        v.z = pack_bf16(__uint_as_float(pa[i][1].x), __uint_as_float(pa[i][1].y));
        v.w = pack_bf16(__uint_as_float(pa[i][1].z), __uint_as_float(pa[i][1].w));
        *(uint4*)&sA[srow[i]][sslot[i]*4] = v;
      }
    } else {
      #pragma unroll
      for(int i=0;i<4;i++)
        *(uint4*)&sA[srow[i]][sslot[i]*4] = pa[i][0];
    }
  };

  f32x4 zero4 = {0.f,0.f,0.f,0.f};
  f32x4 acc[4][4];
  #pragma unroll
  for(int i=0;i<4;i++)
    #pragma unroll
    for(int j=0;j<4;j++) acc[i][j] = zero4;

  int rl = l & 15;
  load_tile(0);
  #pragma unroll
  for(int kt = 0; kt < KT; ++kt){
    store_tile();
    __syncthreads();
    if(kt+1 < KT) load_tile(kt+1);   // A prefetch in flight during MFMA
    #pragma unroll
    for(int ks=0; ks<2; ++ks){
      int koff = ks*16 + (l>>4)*4;
      bf16x8 a[4], b[4];
      #pragma unroll
      for(int f=0; f<4; f++)
        b[f] = *(const bf16x8*)&Wt[(size_t)(wc + f*16 + rl)*K2 + kt*32 + koff];
      #pragma unroll
      for(int f=0; f<4; f++)
        a[f] = *(const bf16x8*)&sA[wr + f*16 + rl][koff];
      #pragma unroll
      for(int i=0;i<4;i++)
        #pragma unroll
        for(int j=0;j<4;j++)
          acc[i][j] = __builtin_amdgcn_mfma_f32_16x16x32_bf16(a[i], b[j], acc[i][j], 0, 0, 0);
    }
    __syncthreads();
  }

  // C-write (direct scatter): col=lane&15, row=(lane>>4)*4+reg
  #pragma unroll
  for(int i=0;i<4;i++){
    #pragma unroll
    for(int j=0;j<4;j++){
      #pragma unroll
      for(int g=0;g<4;g++){
        float v  = acc[i][j][g];
        float vp = __shfl_xor(v, 1);
        if(!(l & 1)){
          unsigned pv = pack_bf16(v, vp);
          int grow = row0 + wr + i*16 + (l>>4)*4 + g;
          int gcol = wc + j*16 + (l&15);
          if(grow < n) outb[(size_t)grow*64 + (gcol>>1)] = pv;
        }
      }
    }
  }

  // fused el/er: wave covers head h = wc>>6 for rows wr..wr+63
  {
    int h = wc >> 6;
    float alv[4], arv[4];
    #pragma unroll
    for(int j=0;j<4;j++){
      int c = wc + j*16 + (l&15);
      alv[j] = al[c]; arv[j] = ar[c];
    }
    #pragma unroll
    for(int i=0;i<4;i++){
      #pragma unroll
      for(int g=0;g<4;g++){
        float pe = acc[i][0][g]*alv[0] + acc[i][1][g]*alv[1]
                 + acc[i][2][g]*alv[2] + acc[i][3][g]*alv[3];
        float qe = acc[i][0][g]*arv[0] + acc[i][1][g]*arv[1]
                 + acc[i][2][g]*arv[2] + acc[i][3][g]*arv[3];
        #pragma unroll
        for(int o=8;o;o>>=1){ pe += __shfl_xor(pe,o); qe += __shfl_xor(qe,o); }
        if((l & 15) == 0){
          int grow = row0 + wr + i*16 + (l>>4)*4 + g;
          if(grow < n){
            el[(size_t)grow*2 + h] = pe;
            er[(size_t)grow*2 + h] = qe;
          }
        }
      }
    }
  }
}

// ---------------- csrD: self-scan of bucket counts + per-bucket rowptr/esrc
__global__ __launch_bounds__(512) void csrD(const unsigned* __restrict__ tmp,
    const int* __restrict__ cursor, int* __restrict__ rowptr,
    int* __restrict__ esrc, int N, int E, int nbuck){
  __shared__ int sc[256];
  __shared__ int hist[512];
  __shared__ int ls[512];
  int t = threadIdx.x;
  int b = blockIdx.x;
  if(t < 256) sc[t] = (t < nbuck) ? cursor[t] : 0;
  __syncthreads();
  for(int o=1;o<256;o<<=1){
    int x = (t>=o && t<256) ? sc[t-o] : 0;
    __syncthreads();
    if(t < 256) sc[t] += x;
    __syncthreads();
  }
  __shared__ int s_base, s_cnt;
  if(t == 0){ s_cnt = cursor[b]; s_base = sc[b] - s_cnt; }
  __syncthreads();
  int base = s_base, cnt = s_cnt;
  const unsigned* tp = tmp + (size_t)b*BCAP;
  int n0 = b << NBUCK_SH;
  int nn = min(512, N - n0);
  hist[t] = 0;
  __syncthreads();
  for(int i = t; i < cnt; i += 512)
    atomicAdd(&hist[tp[i] >> 17], 1);
  __syncthreads();
  int v = hist[t];
  ls[t] = v; __syncthreads();
  for(int o=1;o<512;o<<=1){
    int x = (t>=o) ? ls[t-o] : 0;
    __syncthreads();
    ls[t] += x;
    __syncthreads();
  }
  int rp = ls[t] - v;
  if(t < nn) rowptr[n0 + t] = base + rp;
  if(b == nbuck-1 && t == 0) rowptr[N] = E;
  __syncthreads();
  hist[t] = rp;
  __syncthreads();
  for(int i = t; i < cnt; i += 512){
    unsigned v2 = tp[i];
    int dl = v2 >> 17;
    int s  = v2 & 0x1FFFF;
    int r  = atomicAdd(&hist[dl], 1);
    esrc[base + r] = s;
  }
}

// ---- 8-deep gather/accumulate over one ≤64-edge chunk
__device__ __forceinline__ void agg_chunk(const unsigned* __restrict__ featb,
    int s, unsigned wp, int nval, int lane, int shamt, float& acc0, float& acc1){
  for(int e = 0; e < nval; e += 8){
    unsigned v[8]; float w[8];
    #pragma unroll
    for(int u=0;u<8;u++){
      int se       = __shfl(s,  e+u);
      unsigned wpe = __shfl(wp, e+u);
      w[u] = __uint_as_float((wpe << shamt) & 0xffff0000u);
      v[u] = featb[((unsigned)se << 6) + (unsigned)lane];
    }
    #pragma unroll
    for(int u=0;u<8;u++){
      acc0 += bf_lo(v[u]) * w[u];
      acc1 += bf_hi(v[u]) * w[u];
    }
  }
}

// ---------------- GAT aggregation: wave per dst node, bf16 gather -> bf16 out
__global__ __launch_bounds__(256) void agg_kernel(const unsigned* __restrict__ featb,
    const float* __restrict__ el, const float* __restrict__ er,
    const int* __restrict__ rowptr, const int* __restrict__ esrc,
    const float* __restrict__ bias, unsigned* __restrict__ outp, int n){
  int wid = (blockIdx.x*blockDim.x + threadIdx.x) >> 6;
  int lane = threadIdx.x & 63;
  if(wid >= n) return;
  int beg = rowptr[wid], end = rowptr[wid+1];
  int deg = end - beg;
  float2 erd = *(const float2*)&er[(size_t)wid*2];
  int shamt = (lane < 32) ? 16 : 0;
  float acc0 = 0.f, acc1 = 0.f;

  if(deg <= 64){
    int s = (lane < deg) ? esrc[beg + lane] : 0;
    float2 elv = *(const float2*)&el[(size_t)s*2];
    float e0 = elv.x + erd.x, e1 = elv.y + erd.y;
    e0 = (e0 >= 0.f) ? e0 : SLOPE*e0;
    e1 = (e1 >= 0.f) ? e1 : SLOPE*e1;
    float p0 = __expf(e0), p1 = __expf(e1);
    if(lane >= deg){ p0 = 0.f; p1 = 0.f; }
    float d0 = wave_sum(p0), d1 = wave_sum(p1);
    unsigned wp = pack_bf16(p0 / fmaxf(d0, 1e-16f), p1 / fmaxf(d1, 1e-16f));
    agg_chunk(featb, s, wp, deg, lane, shamt, acc0, acc1);
  } else {
    float d0 = 0.f, d1 = 0.f;
    for(int base = beg; base < end; base += 64){
      int idx = base + lane;
      int s = (idx < end) ? esrc[idx] : 0;
      float2 elv = *(const float2*)&el[(size_t)s*2];
      float e0 = elv.x + erd.x, e1 = elv.y + erd.y;
      e0 = (e0 >= 0.f) ? e0 : SLOPE*e0;
      e1 = (e1 >= 0.f) ? e1 : SLOPE*e1;
      float p0 = __expf(e0), p1 = __expf(e1);
      if(idx >= end){ p0 = 0.f; p1 = 0.f; }
      d0 += p0; d1 += p1;
    }
    d0 = wave_sum(d0); d1 = wave_sum(d1);
    float inv0 = 1.0f / fmaxf(d0, 1e-16f);
    float inv1 = 1.0f / fmaxf(d1, 1e-16f);
    for(int base = beg; base < end; base += 64){
      int idx = base + lane;
      int s = (idx < end) ? esrc[idx] : 0;
      float2 elv = *(const float2*)&el[(size_t)s*2];
      float e0 = elv.x + erd.x, e1 = elv.y + erd.y;
      e0 = (e0 >= 0.f) ? e0 : SLOPE*e0;
      e1 = (e1 >= 0.f) ? e1 : SLOPE*e1;
      unsigned wp = pack_bf16(__expf(e0) * inv0, __expf(e1) * inv1);
      if(idx >= end) wp = 0;
      agg_chunk(featb, s, wp, min(64, end - base), lane, shamt, acc0, acc1);
    }
  }
  float2 bb = *(const float2*)&bias[2*lane];
  outp[(size_t)wid*64 + lane] =
      pack_bf16(fmaxf(acc0 + bb.x, 0.f), fmaxf(acc1 + bb.y, 0.f));
}

// ---------------- head: relu(h@Wout+bout) @ Wfc + bfc + per-block BN partials
__global__ __launch_bounds__(256) void head_kernel(const unsigned* __restrict__ h,
    const float* __restrict__ Wout, const float* __restrict__ bout,
    const float* __restrict__ Wfc, const float* __restrict__ bfc,
    float* __restrict__ hfc, float* __restrict__ psum, float* __restrict__ psum2,
    int n){
  __shared__ float sAT[32][68];
  __shared__ float sWo[32][68];
  __shared__ float sOT[64][68];
  __shared__ float sF [64][68];
  int t = threadIdx.x;
  int cx = t & 15;
  int ry = t >> 4;
  int row0 = blockIdx.x * 64;

  {
    int kr = t >> 4;
    int c0 = (t & 15) * 4;
    #pragma unroll
    for(int i=0;i<4;i++)
      *(float4*)&sF[kr+i*16][c0] = *(const float4*)&Wfc[(size_t)(kr+i*16)*64 + c0];
  }

  float acc[4][4] = {};
  for(int k0 = 0; k0 < 128; k0 += 32){
    #pragma unroll
    for(int u=0;u<2;u++){
      int f4 = t*2 + u;
      int r  = f4 >> 3;
      int kc = (f4 & 7) * 4;
      int gr = row0 + r;
      uint2 v = make_uint2(0,0);
      if(gr < n) v = *(const uint2*)&h[(size_t)gr*64 + ((k0+kc)>>1)];
      sAT[kc+0][r] = bf_lo(v.x);
      sAT[kc+1][r] = bf_hi(v.x);
      sAT[kc+2][r] = bf_lo(v.y);
      sAT[kc+3][r] = bf_hi(v.y);
    }
    #pragma unroll
    for(int u=0;u<2;u++){
      int f4 = t*2 + u;
      int kr = f4 >> 4;
      int c0 = (f4 & 15) * 4;
      *(float4*)&sWo[kr][c0] = *(const float4*)&Wout[(size_t)(k0+kr)*64 + c0];
    }
    __syncthreads();
    #pragma unroll 8
    for(int kk = 0; kk < 32; ++kk){
      float4 a4 = *(const float4*)&sAT[kk][ry*4];
      float4 b4 = *(const float4*)&sWo[kk][cx*4];
      float a[4] = {a4.x,a4.y,a4.z,a4.w};
      float b[4] = {b4.x,b4.y,b4.z,b4.w};
      #pragma unroll
      for(int i=0;i<4;i++)
        #pragma unroll
        for(int j=0;j<4;j++) acc[i][j] += a[i]*b[j];
    }
    __syncthreads();
  }
  {
    float4 bb = *(const float4*)&bout[cx*4];
    float bv[4] = {bb.x,bb.y,bb.z,bb.w};
    #pragma unroll
    for(int i=0;i<4;i++)
      #pragma unroll
      for(int j=0;j<4;j++)
        sOT[cx*4+j][ry*4+i] = fmaxf(acc[i][j] + bv[j], 0.f);
  }
  __syncthreads();
  float acc2[4][4] = {};
  #pragma unroll 8
  for(int kk = 0; kk < 64; ++kk){
    float4 a4 = *(const float4*)&sOT[kk][ry*4];
    float4 b4 = *(const float4*)&sF [kk][cx*4];
    float a[4] = {a4.x,a4.y,a4.z,a4.w};
    float b[4] = {b4.x,b4.y,b4.z,b4.w};
    #pragma unroll
    for(int i=0;i<4;i++)
      #pragma unroll
      for(int j=0;j<4;j++) acc2[i][j] += a[i]*b[j];
  }
  __syncthreads();   // done reading sOT; reuse it for final values
  {
    float4 bb = *(const float4*)&bfc[cx*4];
    float bv[4] = {bb.x,bb.y,bb.z,bb.w};
    #pragma unroll
    for(int i=0;i<4;i++){
      int gr = row0 + ry*4 + i;
      float o0 = acc2[i][0]+bv[0], o1 = acc2[i][1]+bv[1];
      float o2 = acc2[i][2]+bv[2], o3 = acc2[i][3]+bv[3];
      if(gr < n){
        *(float4*)&hfc[(size_t)gr*64 + cx*4] = make_float4(o0,o1,o2,o3);
        sOT[ry*4+i][cx*4+0] = o0;
        sOT[ry*4+i][cx*4+1] = o1;
        sOT[ry*4+i][cx*4+2] = o2;
        sOT[ry*4+i][cx*4+3] = o3;
      } else {
        sOT[ry*4+i][cx*4+0] = 0.f;
        sOT[ry*4+i][cx*4+1] = 0.f;
        sOT[ry*4+i][cx*4+2] = 0.f;
        sOT[ry*4+i][cx*4+3] = 0.f;
      }
    }
  }
  __syncthreads();
  // deterministic per-block column sums over 64 rows
  if(t < 64){
    float s = 0.f, s2 = 0.f;
    #pragma unroll 8
    for(int r = 0; r < 64; ++r){
      float v = sOT[r][t];
      s += v; s2 += v*v;
    }
    psum [(size_t)blockIdx.x*64 + t] = s;
    psum2[(size_t)blockIdx.x*64 + t] = s2;
  }
}

// ---------------- BN reduce stage 1: 128 blocks over nb head-partials
__global__ __launch_bounds__(256) void bn_red(const float* __restrict__ psum,
    const float* __restrict__ psum2, float* __restrict__ rsum,
    float* __restrict__ rsum2, int nb){
  __shared__ float ls[256], ls2[256];
  int t = threadIdx.x; int c = t & 63; int g = t >> 6;
  int R = (nb + 127) / 128;
  int r0 = blockIdx.x * R;
  int r1 = min(nb, r0 + R);
  float s = 0.f, s2 = 0.f;
  for(int r = r0 + g; r < r1; r += 4){
    s  += psum [(size_t)r*64 + c];
    s2 += psum2[(size_t)r*64 + c];
  }
  ls[t] = s; ls2[t] = s2;
  __syncthreads();
  if(t < 64){
    rsum [(size_t)blockIdx.x*64 + t] = ls[t]+ls[t+64]+ls[t+128]+ls[t+192];
    rsum2[(size_t)blockIdx.x*64 + t] = ls2[t]+ls2[t+64]+ls2[t+128]+ls2[t+192];
  }
}

// ---------------- BN finalize (reduces 128 second-level partials)
__global__ __launch_bounds__(256) void bn_fin(const float* __restrict__ rsum,
    const float* __restrict__ rsum2, const float* __restrict__ gamma,
    const float* __restrict__ beta, float* __restrict__ scsh, int n){
  __shared__ float ls[256], ls2[256];
  int t = threadIdx.x; int c = t & 63; int g = t >> 6;
  float s = 0.f, s2 = 0.f;
  for(int b = g; b < 128; b += 4){
    s  += rsum [(size_t)b*64 + c];
    s2 += rsum2[(size_t)b*64 + c];
  }
  ls[t] = s; ls2[t] = s2;
  __syncthreads();
  if(t < 64){
    s  = ls[t]+ls[t+64]+ls[t+128]+ls[t+192];
    s2 = ls2[t]+ls2[t+64]+ls2[t+128]+ls2[t+192];
    float mu  = s / n;
    float var = s2 / n - mu*mu;
    float scale = rsqrtf(var + BN_EPS) * gamma[t];
    scsh[t]    = scale;
    scsh[64+t] = beta[t] - mu*scale;
  }
}

// ---------------- BN apply + row softmax -> p
__global__ __launch_bounds__(256) void bn_softmax(const float* __restrict__ hfc,
    const float* __restrict__ scsh, float* __restrict__ p, int n){
  int wid = (blockIdx.x*blockDim.x + threadIdx.x) >> 6;
  int lane = threadIdx.x & 63;
  if(wid >= n) return;
  float y = hfc[(size_t)wid*64 + lane]*scsh[lane] + scsh[64+lane];
  float m = wave_max(y);
  float e = expf(y - m);
  float s = wave_sum(e);
  p[(size_t)wid*64 + lane] = e / s;
}

// ---------------- loss
__global__ __launch_bounds__(256) void loss1(const float* __restrict__ p,
    const int* __restrict__ train, const int* __restrict__ label,
    float* __restrict__ part, int ntrain){
  int lane = threadIdx.x & 63; int w = threadIdx.x >> 6;
  int gw = blockIdx.x*4 + w; int nw = gridDim.x*4;
  float acc = 0.f;
  for(int t = gw; t < ntrain; t += nw){
    int node = train[t];
    float v = p[(size_t)node*64 + lane];
    float m = wave_max(v);
    float e = expf(v - m);
    float s = wave_sum(e);
    float logp = (v - m) - logf(s);
    int lab = label[node];
    if(lane == lab) acc += logp;
  }
  acc = wave_sum(acc);
  __shared__ float ls[4];
  if(lane == 0) ls[w] = acc;
  __syncthreads();
  if(threadIdx.x == 0) part[blockIdx.x] = ls[0]+ls[1]+ls[2]+ls[3];
}

__global__ void loss2(const float* __restrict__ part, float* __restrict__ out,
                      int nb, int ntrain){
  if(threadIdx.x == 0){
    float s = 0.f;
    for(int i=0;i<nb;i++) s += part[i];
    out[0] = -s / (float)ntrain;
  }
}

extern "C" void kernel_launch(void* const* d_in, const int* in_sizes, int n_in,
                              void* d_out, int out_size, void* d_ws, size_t ws_size,
                              hipStream_t stream){
  const float* feature = (const float*)d_in[0];
  const int*   label   = (const int*)d_in[1];
  const int*   train   = (const int*)d_in[2];
  const int*   src     = (const int*)d_in[3];
  const int*   dst     = (const int*)d_in[4];
  const float* W0   = (const float*)d_in[5];
  const float* al0  = (const float*)d_in[6];
  const float* ar0  = (const float*)d_in[7];
  const float* b0   = (const float*)d_in[8];
  const float* W1   = (const float*)d_in[9];
  const float* al1  = (const float*)d_in[10];
  const float* ar1  = (const float*)d_in[11];
  const float* b1   = (const float*)d_in[12];
  const float* Wout = (const float*)d_in[13];
  const float* bout = (const float*)d_in[14];
  const float* Wfc  = (const float*)d_in[15];
  const float* bfc  = (const float*)d_in[16];
  const float* gamma= (const float*)d_in[17];
  const float* beta = (const float*)d_in[18];

  const int N  = in_sizes[1];
  const int NT = in_sizes[2];
  const int E  = in_sizes[3];

  const int nbuck  = (N + (1<<NBUCK_SH) - 1) >> NBUCK_SH;   // 196
  const int ntiles = (E + CSR_TILE - 1) / CSR_TILE;         // 391
  const int ngemm  = (N + 127) / 128;                       // 782
  const int nhead  = (N + 63) / 64;                         // 1563

  size_t off = 0;
  auto alloc = [&](size_t bytes)->void*{
    void* pp = (char*)d_ws + off;
    off += (bytes + 255) & ~(size_t)255;
    return pp;
  };
  unsigned* featb16 = (unsigned*)alloc((size_t)N*64*4);
  unsigned* hbuf2   = (unsigned*)alloc((size_t)N*64*4);   // also tmp slabs
  float* el      = (float*)alloc((size_t)N*2*4);
  float* er      = (float*)alloc((size_t)N*2*4);
  int*   rowptr  = (int*)alloc((size_t)(N+1)*4);
  int*   esrc    = (int*)alloc((size_t)E*4);
  int*   cursor  = (int*)alloc((size_t)256*4);
  unsigned* Wt0  = (unsigned*)alloc((size_t)128*128*4);
  unsigned* Wt1  = (unsigned*)alloc((size_t)128*64*4);
  float* psum    = (float*)alloc((size_t)(nhead+1)*64*4);
  float* psum2   = (float*)alloc((size_t)(nhead+1)*64*4);
  float* rsum    = (float*)alloc((size_t)128*64*4);
  float* rsum2   = (float*)alloc((size_t)128*64*4);
  float* scsh    = (float*)alloc(128*4);
  float* lpart   = (float*)alloc(256*4);
  float* hfc     = (float*)featb16;      // reuse: featb16 dead after agg L1
  unsigned* tmp  = hbuf2;                // reuse: hbuf2 first written by agg L0

  float* p_out   = (float*)d_out;
  float* loss_out= (float*)d_out + (size_t)N*64;

  const int nwaveblk = (N + 3) / 4;

  // 1. weight prep + cursor zeroing
  wtrans2<<<96, 256, 0, stream>>>(W0, W1, Wt0, Wt1, cursor);

  // 2. CSR scatter || GEMM layer 0 (independent; one fat dispatch)
  fat_kernel<1,256><<<ntiles + ngemm, 256, 0, stream>>>(feature, Wt0, featb16,
      al0, ar0, el, er, N, src, dst, cursor, tmp, E, nbuck, ntiles);

  // 3. CSR finalize
  csrD<<<nbuck, 512, 0, stream>>>(tmp, cursor, rowptr, esrc, N, E, nbuck);

  // 4. aggregation layer 0
  agg_kernel<<<nwaveblk, 256, 0, stream>>>(featb16, el, er, rowptr, esrc, b0, hbuf2, N);

  // 5. GEMM layer 1 (ncsr = 0)
  fat_kernel<0,128><<<ngemm, 256, 0, stream>>>(hbuf2, Wt1, featb16,
      al1, ar1, el, er, N, src, dst, cursor, tmp, E, nbuck, 0);

  // 6. aggregation layer 1
  agg_kernel<<<nwaveblk, 256, 0, stream>>>(featb16, el, er, rowptr, esrc, b1, hbuf2, N);

  // 7. dense head + BN partials
  head_kernel<<<nhead, 256, 0, stream>>>(hbuf2, Wout, bout, Wfc, bfc, hfc, psum, psum2, N);

  // 8. BN reduce (two-stage deterministic tree)
  bn_red<<<128, 256, 0, stream>>>(psum, psum2, rsum, rsum2, nhead);
  bn_fin<<<1, 256, 0, stream>>>(rsum, rsum2, gamma, beta, scsh, N);

  // 9. BN apply + softmax
  bn_softmax<<<nwaveblk, 256, 0, stream>>>(hfc, scsh, p_out, N);

  // 10-11. loss
  loss1<<<40, 256, 0, stream>>>(p_out, train, label, lpart, NT);
  loss2<<<1, 64, 0, stream>>>(lpart, loss_out, 40, NT);
}